// Round 9
// baseline (300.634 us; speedup 1.0000x reference)
//
#include <hip/hip_runtime.h>

typedef unsigned int   uint_ma   __attribute__((may_alias));
typedef unsigned short ushort_ma __attribute__((may_alias));
typedef float          float_ma  __attribute__((may_alias));
typedef __bf16 bf16x8 __attribute__((ext_vector_type(8)));
typedef float f32x4 __attribute__((ext_vector_type(4)));
typedef uint_ma u32x4 __attribute__((ext_vector_type(4)));
typedef uint_ma u32x2 __attribute__((ext_vector_type(2)));
typedef ushort_ma u16x4 __attribute__((ext_vector_type(4)));

#define BATCH 8
#define NTOK 2304
#define CDIM 512
#define NH 8
#define HD 64
#define MROWS (BATCH * NTOK)  // 18432
#define LOG2E 1.44269504088896f

// ---- workspace layout (bf16 element offsets) ------------------------------
constexpr size_t N_X  = (size_t)BATCH * NTOK * CDIM;  // 9,437,184
constexpr size_t N_WQ = (size_t)3 * CDIM * CDIM;      //   786,432
constexpr size_t N_WP = (size_t)CDIM * CDIM;          //   262,144
constexpr size_t OFF_XO = 0;              // X for gemm1; O overlay after
constexpr size_t OFF_WQ = OFF_XO + N_X;
constexpr size_t OFF_WP = OFF_WQ + N_WQ;
constexpr size_t OFF_Q  = OFF_WP + N_WP;
constexpr size_t OFF_K  = OFF_Q + N_X;
constexpr size_t OFF_V  = OFF_K + N_X;
constexpr size_t CV8 = (N_X + N_WQ + N_WP) / 8;  // 1,310,720

__device__ __forceinline__ float bf2f(unsigned short h) {
  unsigned int u = ((unsigned int)h) << 16;
  return __builtin_bit_cast(float, u);
}
__device__ __forceinline__ unsigned short f2bf(float f) {
  unsigned int u = __builtin_bit_cast(unsigned int, f);
  u += 0x7fffu + ((u >> 16) & 1u);  // RNE
  return (unsigned short)(u >> 16);
}

// async global -> LDS, 16B per lane (dest = wave-uniform base + lane*16)
__device__ __forceinline__ void gload16(const void* g, void* l) {
  __builtin_amdgcn_global_load_lds(
      (const __attribute__((address_space(1))) void*)g,
      (__attribute__((address_space(3))) void*)l, 16, 0, 0);
}

// ---------------------------------------------------------------------------
// Convert x, qkv_w, proj_w (fp32) -> bf16 in ws.
// ---------------------------------------------------------------------------
__global__ __launch_bounds__(256) void convert3(
    const float* __restrict__ s0, const float* __restrict__ s1,
    const float* __restrict__ s2, ushort_ma* __restrict__ base) {
  const size_t gid = (size_t)blockIdx.x * blockDim.x + threadIdx.x;
  const size_t stride = (size_t)gridDim.x * blockDim.x;
  for (size_t i = gid; i < CV8; i += stride) {
    size_t r = i;
    const float* src;
    size_t doff;
    if (r < N_X / 8) { src = s0; doff = OFF_XO; }
    else if ((r -= N_X / 8) < N_WQ / 8) { src = s1; doff = OFF_WQ; }
    else { r -= N_WQ / 8; src = s2; doff = OFF_WP; }
    const f32x4* fw = (const f32x4*)(src + r * 8);
    const f32x4 a = fw[0], b = fw[1];
    u16x4 lo, hi;
#pragma unroll
    for (int j = 0; j < 4; j++) { lo[j] = f2bf(a[j]); hi[j] = f2bf(b[j]); }
    ushort_ma* dst = base + doff + r * 8;
    *(u16x4*)dst = lo;
    *(u16x4*)(dst + 4) = hi;
  }
}

// ---------------------------------------------------------------------------
// C = A (M x 512) * W^T (contraction K=512), m97-style staging:
// global_load_lds width=16, double-buffered LDS, 1 barrier/iter.
// XOR column swizzle: LDS[row][8c] holds global col-group c ^ ((row>>1)&3).
// MFMA operands swapped (mfma(bfr, af)) so the C fragment is transposed:
// each lane's 4 acc values are 4 consecutive OUTPUT COLUMNS at one row.
//   MODE 0: Q and K written as u16x4 (4 consecutive d); V^T scalar
//   MODE 1: fp32 out written as global_store_dwordx4
// (R9/R13/R15 HW-proven passing.)
// ---------------------------------------------------------------------------
template <int MODE>
__global__ __launch_bounds__(256, 3) void gemm_bt(
    const ushort_ma* __restrict__ A, const ushort_ma* __restrict__ W,
    const float* __restrict__ aux,   // MODE0: temperature[8]; MODE1: proj_b[512]
    unsigned short* __restrict__ o0, // MODE0: Q (64,2304,64); MODE1: fp32 out
    unsigned short* __restrict__ o1, // MODE0: K (64,2304,64)
    unsigned short* __restrict__ o2) // MODE0: Vt (64,64,2304)
{
  __shared__ __align__(16) ushort_ma As[2][128][32];
  __shared__ __align__(16) ushort_ma Bs[2][128][32];
  const int K = CDIM;
  const int m0 = blockIdx.x * 128;
  const int n0 = blockIdx.y * 128;
  const int t = threadIdx.x;
  const int lane = t & 63;
  const int w = t >> 6;
  const int wm = (w >> 1) * 64, wn = (w & 1) * 64;
  const int lr = lane & 15, lq = lane >> 4;

  const int srow = w * 16 + (lane >> 2);
  const int scg = (lane & 3) ^ ((srow >> 1) & 3);
  const ushort_ma* Ag0 = A + (size_t)(m0 + srow) * K + scg * 8;
  const ushort_ma* Ag1 = Ag0 + (size_t)64 * K;
  const ushort_ma* Bg0 = W + (size_t)(n0 + srow) * K + scg * 8;
  const ushort_ma* Bg1 = Bg0 + (size_t)64 * K;

  const f32x4 fz = {0.f, 0.f, 0.f, 0.f};
  f32x4 acc[4][4];
#pragma unroll
  for (int i = 0; i < 4; i++)
#pragma unroll
    for (int j = 0; j < 4; j++) acc[i][j] = fz;

  auto issue = [&](int kt, int buf) {
    const int k0 = kt * 32;
    gload16(Ag0 + k0, (void*)&As[buf][w * 16][0]);
    gload16(Ag1 + k0, (void*)&As[buf][64 + w * 16][0]);
    gload16(Bg0 + k0, (void*)&Bs[buf][w * 16][0]);
    gload16(Bg1 + k0, (void*)&Bs[buf][64 + w * 16][0]);
  };

  issue(0, 0);
  const int colf = 8 * (lq ^ ((lr >> 1) & 3));

  for (int kt = 0; kt < 16; kt++) {
    const int buf = kt & 1;
    __syncthreads();  // drains vmcnt(0): tile kt landed; prev readers done
    if (kt < 15) issue(kt + 1, buf ^ 1);
    bf16x8 af[4], bfr[4];
#pragma unroll
    for (int i = 0; i < 4; i++)
      af[i] = __builtin_bit_cast(bf16x8, *(const u32x4*)(&As[buf][wm + i * 16 + lr][colf]));
#pragma unroll
    for (int j = 0; j < 4; j++)
      bfr[j] = __builtin_bit_cast(bf16x8, *(const u32x4*)(&Bs[buf][wn + j * 16 + lr][colf]));
#pragma unroll
    for (int i = 0; i < 4; i++)
#pragma unroll
      for (int j = 0; j < 4; j++)
        acc[i][j] = __builtin_amdgcn_mfma_f32_16x16x32_bf16(bfr[j], af[i], acc[i][j], 0, 0, 0);
  }

  // Epilogue, transposed-C layout: acc[i][j][r] = C[gm][gc] with
  //   gm = m0 + wm + i*16 + lr
  //   gc = n0 + wn + j*16 + lq*4 + r
  if (MODE == 0) {
#pragma unroll
    for (int j = 0; j < 4; j++) {
      const int gcb = n0 + wn + j * 16 + lq * 4;  // 4-aligned, no 64/512 straddle
      const int which = gcb >> 9;  // 0=q,1=k,2=v (uniform over r)
      const int h = (gcb >> 6) & 7;
      const int db = gcb & 63;
      // Q carries exp(temperature)*log2e so attention works in log2 domain
      const float sc = (which == 0) ? __expf(aux[h]) * LOG2E : 1.0f;
      unsigned short* dst = (which == 0) ? o0 : o1;
#pragma unroll
      for (int i = 0; i < 4; i++) {
        const int gm = m0 + wm + i * 16 + lr;
        const int b = gm / NTOK;
        const int np = gm - b * NTOK;
        if (which == 2) {
#pragma unroll
          for (int r = 0; r < 4; r++)
            o2[((size_t)((b * NH + h) * HD + db + r)) * NTOK + np] = f2bf(acc[i][j][r]);
        } else {
          u16x4 pk;
#pragma unroll
          for (int r = 0; r < 4; r++) pk[r] = f2bf(acc[i][j][r] * sc);
          *(u16x4*)(dst + ((size_t)((b * NH + h) * NTOK + np)) * HD + db) = pk;
        }
      }
    }
  } else {
    float_ma* outf = (float_ma*)o0;
#pragma unroll
    for (int j = 0; j < 4; j++) {
      const int gcb = n0 + wn + j * 16 + lq * 4;
      const f32x4 bv4 = *(const f32x4*)(aux + gcb);
#pragma unroll
      for (int i = 0; i < 4; i++) {
        const int gm = m0 + wm + i * 16 + lr;
        f32x4 ov;
#pragma unroll
        for (int r = 0; r < 4; r++) ov[r] = acc[i][j][r] + bv4[r];
        *(f32x4*)(outf + (size_t)gm * CDIM + gcb) = ov;
      }
    }
  }
}

// ---------------------------------------------------------------------------
// Flash attention, log2-domain, no max tracking; bias folded into the QK MFMA
// via the rank-4 K-dim extension (R6-proven).
// R16 = R15 + two latency levers (no new fragment/layout semantics):
//  * P-round-trip software pipeline: Ps double-buffered ([4][2][32][36],
//    stride 36 = R15's proven conflict-free layout).  Prologue computes
//    S(0)+writes P(0); each iter does computeS(c+1) -> lgkmcnt(0) ->
//    read aP(c) -> PV(c)+l(c) -> write P(c+1).  The fence now hides behind
//    ~12 MFMAs + 6 LDS reads of independent work instead of directly
//    following the writes.  LDS 54272 B x 3 = 162816 <= 163840 -> still
//    3 blocks/CU.  Single s2 register set (dead between packwrite(c) and
//    computeS(c+1)), so ~zero VGPR cost.
//  * XCD-aware block swizzle: 1D grid 1152; v = (bid&7)*144 + (bid>>3)
//    gives each XCD 8 exclusive bh values -> K/V fetched ~once per XCD
//    (FETCH_SIZE is the observable).
// Kept (HW-proven): S^T orientation, Ks[128][72] + bias-in-LDS broadcast
// k-step, Q fragments direct from global, short-live-range staging,
// lgkmcnt(0) fence before aP reads, s_setprio around MFMA clusters.
// ---------------------------------------------------------------------------
__global__ __launch_bounds__(256, 3) void attn_kernel(
    const ushort_ma* __restrict__ Qg,  // (64, 2304, 64), pre-scaled
    const ushort_ma* __restrict__ Kg,  // (64, 2304, 64)
    const ushort_ma* __restrict__ Vg,  // (64, 64, 2304)  (V^T)
    const float* __restrict__ lwp,     // locality_weight fp32 [8]
    unsigned short* __restrict__ Og)   // (8, 2304, 512): b, np, h*64+d
{
  __shared__ __align__(16) ushort_ma Ks[128][72];
  __shared__ __align__(16) ushort_ma Vs[64][136];
  __shared__ __align__(16) ushort_ma Ps[4][2][32][36];
  // total LDS = 18432 + 17408 + 18432 = 54272 B -> 3 blocks/CU (x3 = 162816)

  // XCD-aware swizzle: 1152 blocks = 8 XCDs x 144; give each XCD 8 whole bh
  const int orig = blockIdx.x;
  const int v = (orig & 7) * 144 + (orig >> 3);
  const int bh = v / 18;
  const int q0 = (v - bh * 18) * 128;
  const int b = bh >> 3, h = bh & 7;
  const int t = threadIdx.x;
  const int lane = t & 63;
  const int w = t >> 6;
  const int lr = lane & 15, lq = lane >> 4;

  // Q fragments straight from global: rows are contiguous 128 B -> coalesced.
  const ushort_ma* Qw = Qg + ((size_t)bh * NTOK + q0 + (size_t)w * 32) * HD;
  bf16x8 aQ[2][2];
#pragma unroll
  for (int mi = 0; mi < 2; mi++)
#pragma unroll
    for (int ks = 0; ks < 2; ks++)
      aQ[mi][ks] = __builtin_bit_cast(
          bf16x8, *(const u32x4*)(Qw + (size_t)(mi * 16 + lr) * HD + ks * 32 + lq * 8));

  const float cb2 = -0.5f * LOG2E * lwp[h];  // bias_log2 = cb2 * dist2
  // Q-side bias extension fragment (n=lr; k slots on lq==0 only)
  bf16x8 aQb[2];
#pragma unroll
  for (int mi = 0; mi < 2; mi++) {
    const int qrow = q0 + w * 32 + mi * 16 + lr;
    const int yy = qrow / 48;
    const int xx = qrow - yy * 48;
    const float fy = (float)yy * (1.0f / 47.0f);
    const float fx = (float)xx * (1.0f / 47.0f);
    u32x4 vv = {0u, 0u, 0u, 0u};
    if (lq == 0) {
      vv[0] = (unsigned int)f2bf(fy) | ((unsigned int)f2bf(fx) << 16);
      vv[1] = (unsigned int)f2bf(fy * fy + fx * fx) | (0x3F80u << 16);
    }
    aQb[mi] = __builtin_bit_cast(bf16x8, vv);
  }

  // ones B-fragment for the l-MFMA
  const u32x4 onesU = {0x3F803F80u, 0x3F803F80u, 0x3F803F80u, 0x3F803F80u};
  const bf16x8 bOnes = __builtin_bit_cast(bf16x8, onesU);

  const f32x4 fz = {0.f, 0.f, 0.f, 0.f};
  f32x4 accO[2][4];
  f32x4 accL[2];
#pragma unroll
  for (int mi = 0; mi < 2; mi++) {
    accL[mi] = fz;
#pragma unroll
    for (int nd = 0; nd < 4; nd++) accO[mi][nd] = fz;
  }

  const ushort_ma* Kb = Kg + (size_t)bh * NTOK * HD;
  const ushort_ma* Vb = Vg + (size_t)bh * HD * NTOK;

  // S-MFMA for chunk cc (2 data k-steps + bias broadcast), into out[2][2]
  auto computeS = [&](int cc, f32x4 (&out)[2][2]) {
#pragma unroll
    for (int mi = 0; mi < 2; mi++) { out[mi][0] = fz; out[mi][1] = fz; }
    __builtin_amdgcn_s_setprio(1);
#pragma unroll
    for (int e2 = 0; e2 < 2; e2++) {
      const int ni = 2 * cc + e2;
#pragma unroll
      for (int ks = 0; ks < 2; ks++) {
        const bf16x8 bK = __builtin_bit_cast(
            bf16x8, *(const u32x4*)(&Ks[ni * 16 + lr][ks * 32 + lq * 8]));
#pragma unroll
        for (int mi = 0; mi < 2; mi++)
          out[mi][e2] = __builtin_amdgcn_mfma_f32_16x16x32_bf16(bK, aQ[mi][ks], out[mi][e2], 0, 0, 0);
      }
      // bias k-step: broadcast b128 (same addr across lq -> 2-way, free);
      // wrong-k lanes multiply aQb's zeros.
      const bf16x8 bKb = __builtin_bit_cast(
          bf16x8, *(const u32x4*)(&Ks[ni * 16 + lr][64]));
#pragma unroll
      for (int mi = 0; mi < 2; mi++)
        out[mi][e2] = __builtin_amdgcn_mfma_f32_16x16x32_bf16(bKb, aQb[mi], out[mi][e2], 0, 0, 0);
    }
    __builtin_amdgcn_s_setprio(0);
  };

  // exp2 + pack + ds_write_b64 into Ps buffer (cc&1)
  auto packP = [&](int cc, f32x4 (&sin)[2][2]) {
    const int bf = cc & 1;
#pragma unroll
    for (int mi = 0; mi < 2; mi++)
#pragma unroll
      for (int e2 = 0; e2 < 2; e2++) {
        unsigned int pb[4];
#pragma unroll
        for (int r = 0; r < 4; r++) {
          const float p = __builtin_amdgcn_exp2f(sin[mi][e2][r]);
          pb[r] = (__builtin_bit_cast(unsigned int, p) >> 16) & 0xFFFFu;
        }
        u32x2 pk;
        pk[0] = pb[0] | (pb[1] << 16);
        pk[1] = pb[2] | (pb[3] << 16);
        *(u32x2*)(&Ps[w][bf][mi * 16 + lr][e2 * 16 + lq * 4]) = pk;
      }
  };

  for (int kt = 0; kt < 18; kt++) {
    const int kv0 = kt * 128;
    __syncthreads();  // WAR: previous tile's readers done
    {
      u32x4 kc[4], vc[4];
#pragma unroll
      for (int it = 0; it < 4; it++) {
        const int q = t + it * 256;
        kc[it] = *(const u32x4*)(Kb + (size_t)(kv0 + (q >> 3)) * HD + (q & 7) * 8);
        vc[it] = *(const u32x4*)(Vb + (size_t)(q >> 4) * NTOK + kv0 + (q & 15) * 8);
      }
#pragma unroll
      for (int it = 0; it < 4; it++) {
        const int q = t + it * 256;
        *(u32x4*)(&Ks[q >> 3][(q & 7) * 8]) = kc[it];
        *(u32x4*)(&Vs[q >> 4][(q & 15) * 8]) = vc[it];
      }
    }
    // K-side bias extension for this tile's 128 kv rows (cols 64..71),
    // computed ONCE per tile by 128 threads
    if (t < 128) {
      const int kv = kv0 + t;
      const int yy = kv / 48;
      const int xx = kv - yy * 48;
      const float fy = (float)yy * (1.0f / 47.0f);
      const float fx = (float)xx * (1.0f / 47.0f);
      u32x4 bv;
      bv[0] = (unsigned int)f2bf(-2.0f * cb2 * fy) |
              ((unsigned int)f2bf(-2.0f * cb2 * fx) << 16);
      bv[1] = (unsigned int)f2bf(cb2) |
              ((unsigned int)f2bf(cb2 * (fy * fy + fx * fx)) << 16);
      bv[2] = 0u;
      bv[3] = 0u;
      *(u32x4*)(&Ks[t][64]) = bv;
    }
    __syncthreads();  // tile ready

    // pipelined chunk loop: fence hides behind next chunk's S-MFMAs
    f32x4 s2[2][2];
    computeS(0, s2);
    packP(0, s2);
#pragma unroll
    for (int c = 0; c < 4; c++) {
      if (c < 3) computeS(c + 1, s2);
      // HW completion fence: P(c) writes (issued one iteration ago, with the
      // whole S-MFMA cluster in between) are drained here
      __asm__ volatile("s_waitcnt lgkmcnt(0)" ::: "memory");
      bf16x8 aP[2];
#pragma unroll
      for (int mi = 0; mi < 2; mi++)
        aP[mi] = __builtin_bit_cast(
            bf16x8, *(const u32x4*)(&Ps[w][c & 1][mi * 16 + lr][lq * 8]));
      __builtin_amdgcn_s_setprio(1);
#pragma unroll
      for (int nd = 0; nd < 4; nd++) {
        const bf16x8 bV = __builtin_bit_cast(
            bf16x8, *(const u32x4*)(&Vs[nd * 16 + lr][c * 32 + lq * 8]));
#pragma unroll
        for (int mi = 0; mi < 2; mi++)
          accO[mi][nd] = __builtin_amdgcn_mfma_f32_16x16x32_bf16(aP[mi], bV, accO[mi][nd], 0, 0, 0);
      }
      // l += P x ones (exact same aP operand -> perfect num/denom consistency)
#pragma unroll
      for (int mi = 0; mi < 2; mi++)
        accL[mi] = __builtin_amdgcn_mfma_f32_16x16x32_bf16(aP[mi], bOnes, accL[mi], 0, 0, 0);
      __builtin_amdgcn_s_setprio(0);
      if (c < 3) packP(c + 1, s2);
    }
  }

  // normalize and store: accL C-layout row matches accO row exactly
#pragma unroll
  for (int mi = 0; mi < 2; mi++) {
    f32x4 inv;
#pragma unroll
    for (int r = 0; r < 4; r++) inv[r] = 1.0f / accL[mi][r];
#pragma unroll
    for (int nd = 0; nd < 4; nd++)
#pragma unroll
      for (int r = 0; r < 4; r++) {
        const int np = q0 + w * 32 + mi * 16 + lq * 4 + r;
        Og[((size_t)(b * NTOK + np)) * CDIM + h * HD + nd * 16 + lr] =
            f2bf(accO[mi][nd][r] * inv[r]);
      }
  }
}

extern "C" void kernel_launch(void* const* d_in, const int* in_sizes, int n_in,
                              void* d_out, int out_size, void* d_ws, size_t ws_size,
                              hipStream_t stream) {
  const float* x      = (const float*)d_in[0];
  const float* qkv_w  = (const float*)d_in[1];
  const float* proj_w = (const float*)d_in[2];
  const float* proj_b = (const float*)d_in[3];
  const float* temp   = (const float*)d_in[4];
  const float* lw     = (const float*)d_in[5];

  ushort_ma* base = (ushort_ma*)d_ws;
  ushort_ma* XB  = base + OFF_XO;   // x bf16; overlaid by O after gemm1
  ushort_ma* WQB = base + OFF_WQ;
  ushort_ma* WPB = base + OFF_WP;
  ushort_ma* Q   = base + OFF_Q;
  ushort_ma* Kt  = base + OFF_K;
  ushort_ma* Vt  = base + OFF_V;
  ushort_ma* O   = XB;              // overlay: XB dead after gemm1

  convert3<<<1024, 256, 0, stream>>>(x, qkv_w, proj_w, base);
  gemm_bt<0><<<dim3(MROWS / 128, 1536 / 128), 256, 0, stream>>>(
      XB, WQB, temp, (unsigned short*)Q, (unsigned short*)Kt, (unsigned short*)Vt);
  attn_kernel<<<dim3((NTOK / 128) * BATCH * NH), 256, 0, stream>>>(
      Q, Kt, Vt, lw, (unsigned short*)O);
  gemm_bt<1><<<dim3(MROWS / 128, CDIM / 128), 256, 0, stream>>>(
      O, WPB, proj_b, (unsigned short*)d_out, nullptr, nullptr);
}

// Round 10
// 294.102 us; speedup vs baseline: 1.0222x; 1.0222x over previous
//
#include <hip/hip_runtime.h>

typedef unsigned int   uint_ma   __attribute__((may_alias));
typedef unsigned short ushort_ma __attribute__((may_alias));
typedef float          float_ma  __attribute__((may_alias));
typedef __bf16 bf16x8 __attribute__((ext_vector_type(8)));
typedef float f32x4 __attribute__((ext_vector_type(4)));
typedef uint_ma u32x4 __attribute__((ext_vector_type(4)));
typedef uint_ma u32x2 __attribute__((ext_vector_type(2)));
typedef ushort_ma u16x4 __attribute__((ext_vector_type(4)));

#define BATCH 8
#define NTOK 2304
#define CDIM 512
#define NH 8
#define HD 64
#define MROWS (BATCH * NTOK)  // 18432
#define LOG2E 1.44269504088896f

// ---- workspace layout (bf16 element offsets) ------------------------------
constexpr size_t N_X  = (size_t)BATCH * NTOK * CDIM;  // 9,437,184
constexpr size_t N_WQ = (size_t)3 * CDIM * CDIM;      //   786,432
constexpr size_t N_WP = (size_t)CDIM * CDIM;          //   262,144
constexpr size_t OFF_XO = 0;              // X for gemm1; O overlay after
constexpr size_t OFF_WQ = OFF_XO + N_X;
constexpr size_t OFF_WP = OFF_WQ + N_WQ;
constexpr size_t OFF_Q  = OFF_WP + N_WP;
constexpr size_t OFF_K  = OFF_Q + N_X;
constexpr size_t OFF_V  = OFF_K + N_X;
constexpr size_t CV8 = (N_X + N_WQ + N_WP) / 8;  // 1,310,720

__device__ __forceinline__ float bf2f(unsigned short h) {
  unsigned int u = ((unsigned int)h) << 16;
  return __builtin_bit_cast(float, u);
}
__device__ __forceinline__ unsigned short f2bf(float f) {
  unsigned int u = __builtin_bit_cast(unsigned int, f);
  u += 0x7fffu + ((u >> 16) & 1u);  // RNE
  return (unsigned short)(u >> 16);
}

// async global -> LDS, 16B per lane (dest = wave-uniform base + lane*16)
__device__ __forceinline__ void gload16(const void* g, void* l) {
  __builtin_amdgcn_global_load_lds(
      (const __attribute__((address_space(1))) void*)g,
      (__attribute__((address_space(3))) void*)l, 16, 0, 0);
}

// ---------------------------------------------------------------------------
// Convert x, qkv_w, proj_w (fp32) -> bf16 in ws.
// ---------------------------------------------------------------------------
__global__ __launch_bounds__(256) void convert3(
    const float* __restrict__ s0, const float* __restrict__ s1,
    const float* __restrict__ s2, ushort_ma* __restrict__ base) {
  const size_t gid = (size_t)blockIdx.x * blockDim.x + threadIdx.x;
  const size_t stride = (size_t)gridDim.x * blockDim.x;
  for (size_t i = gid; i < CV8; i += stride) {
    size_t r = i;
    const float* src;
    size_t doff;
    if (r < N_X / 8) { src = s0; doff = OFF_XO; }
    else if ((r -= N_X / 8) < N_WQ / 8) { src = s1; doff = OFF_WQ; }
    else { r -= N_WQ / 8; src = s2; doff = OFF_WP; }
    const f32x4* fw = (const f32x4*)(src + r * 8);
    const f32x4 a = fw[0], b = fw[1];
    u16x4 lo, hi;
#pragma unroll
    for (int j = 0; j < 4; j++) { lo[j] = f2bf(a[j]); hi[j] = f2bf(b[j]); }
    ushort_ma* dst = base + doff + r * 8;
    *(u16x4*)dst = lo;
    *(u16x4*)(dst + 4) = hi;
  }
}

// ---------------------------------------------------------------------------
// C = A (M x 512) * W^T (contraction K=512), m97-style staging:
// global_load_lds width=16, double-buffered LDS, 1 barrier/iter.
// XOR column swizzle: LDS[row][8c] holds global col-group c ^ ((row>>1)&3).
// MFMA operands swapped (mfma(bfr, af)) so the C fragment is transposed:
// each lane's 4 acc values are 4 consecutive OUTPUT COLUMNS at one row.
//   MODE 0: Q and K written as u16x4 (4 consecutive d); V^T scalar
//   MODE 1: fp32 out written as global_store_dwordx4
// (R9/R13/R15 HW-proven passing.)
// ---------------------------------------------------------------------------
template <int MODE>
__global__ __launch_bounds__(256, 3) void gemm_bt(
    const ushort_ma* __restrict__ A, const ushort_ma* __restrict__ W,
    const float* __restrict__ aux,   // MODE0: temperature[8]; MODE1: proj_b[512]
    unsigned short* __restrict__ o0, // MODE0: Q (64,2304,64); MODE1: fp32 out
    unsigned short* __restrict__ o1, // MODE0: K (64,2304,64)
    unsigned short* __restrict__ o2) // MODE0: Vt (64,64,2304)
{
  __shared__ __align__(16) ushort_ma As[2][128][32];
  __shared__ __align__(16) ushort_ma Bs[2][128][32];
  const int K = CDIM;
  const int m0 = blockIdx.x * 128;
  const int n0 = blockIdx.y * 128;
  const int t = threadIdx.x;
  const int lane = t & 63;
  const int w = t >> 6;
  const int wm = (w >> 1) * 64, wn = (w & 1) * 64;
  const int lr = lane & 15, lq = lane >> 4;

  const int srow = w * 16 + (lane >> 2);
  const int scg = (lane & 3) ^ ((srow >> 1) & 3);
  const ushort_ma* Ag0 = A + (size_t)(m0 + srow) * K + scg * 8;
  const ushort_ma* Ag1 = Ag0 + (size_t)64 * K;
  const ushort_ma* Bg0 = W + (size_t)(n0 + srow) * K + scg * 8;
  const ushort_ma* Bg1 = Bg0 + (size_t)64 * K;

  const f32x4 fz = {0.f, 0.f, 0.f, 0.f};
  f32x4 acc[4][4];
#pragma unroll
  for (int i = 0; i < 4; i++)
#pragma unroll
    for (int j = 0; j < 4; j++) acc[i][j] = fz;

  auto issue = [&](int kt, int buf) {
    const int k0 = kt * 32;
    gload16(Ag0 + k0, (void*)&As[buf][w * 16][0]);
    gload16(Ag1 + k0, (void*)&As[buf][64 + w * 16][0]);
    gload16(Bg0 + k0, (void*)&Bs[buf][w * 16][0]);
    gload16(Bg1 + k0, (void*)&Bs[buf][64 + w * 16][0]);
  };

  issue(0, 0);
  const int colf = 8 * (lq ^ ((lr >> 1) & 3));

  for (int kt = 0; kt < 16; kt++) {
    const int buf = kt & 1;
    __syncthreads();  // drains vmcnt(0): tile kt landed; prev readers done
    if (kt < 15) issue(kt + 1, buf ^ 1);
    bf16x8 af[4], bfr[4];
#pragma unroll
    for (int i = 0; i < 4; i++)
      af[i] = __builtin_bit_cast(bf16x8, *(const u32x4*)(&As[buf][wm + i * 16 + lr][colf]));
#pragma unroll
    for (int j = 0; j < 4; j++)
      bfr[j] = __builtin_bit_cast(bf16x8, *(const u32x4*)(&Bs[buf][wn + j * 16 + lr][colf]));
#pragma unroll
    for (int i = 0; i < 4; i++)
#pragma unroll
      for (int j = 0; j < 4; j++)
        acc[i][j] = __builtin_amdgcn_mfma_f32_16x16x32_bf16(bfr[j], af[i], acc[i][j], 0, 0, 0);
  }

  // Epilogue, transposed-C layout: acc[i][j][r] = C[gm][gc] with
  //   gm = m0 + wm + i*16 + lr
  //   gc = n0 + wn + j*16 + lq*4 + r
  if (MODE == 0) {
#pragma unroll
    for (int j = 0; j < 4; j++) {
      const int gcb = n0 + wn + j * 16 + lq * 4;  // 4-aligned, no 64/512 straddle
      const int which = gcb >> 9;  // 0=q,1=k,2=v (uniform over r)
      const int h = (gcb >> 6) & 7;
      const int db = gcb & 63;
      // Q carries exp(temperature)*log2e so attention works in log2 domain
      const float sc = (which == 0) ? __expf(aux[h]) * LOG2E : 1.0f;
      unsigned short* dst = (which == 0) ? o0 : o1;
#pragma unroll
      for (int i = 0; i < 4; i++) {
        const int gm = m0 + wm + i * 16 + lr;
        const int b = gm / NTOK;
        const int np = gm - b * NTOK;
        if (which == 2) {
#pragma unroll
          for (int r = 0; r < 4; r++)
            o2[((size_t)((b * NH + h) * HD + db + r)) * NTOK + np] = f2bf(acc[i][j][r]);
        } else {
          u16x4 pk;
#pragma unroll
          for (int r = 0; r < 4; r++) pk[r] = f2bf(acc[i][j][r] * sc);
          *(u16x4*)(dst + ((size_t)((b * NH + h) * NTOK + np)) * HD + db) = pk;
        }
      }
    }
  } else {
    float_ma* outf = (float_ma*)o0;
#pragma unroll
    for (int j = 0; j < 4; j++) {
      const int gcb = n0 + wn + j * 16 + lq * 4;
      const f32x4 bv4 = *(const f32x4*)(aux + gcb);
#pragma unroll
      for (int i = 0; i < 4; i++) {
        const int gm = m0 + wm + i * 16 + lr;
        f32x4 ov;
#pragma unroll
        for (int r = 0; r < 4; r++) ov[r] = acc[i][j][r] + bv4[r];
        *(f32x4*)(outf + (size_t)gm * CDIM + gcb) = ov;
      }
    }
  }
}

// ---------------------------------------------------------------------------
// Flash attention, log2-domain, no max tracking; bias folded into the QK MFMA
// via the rank-4 K-dim extension (R6-proven).
// R17 = R15 (single Ps buffer, 45056 B LDS -> 3 blocks/CU; R16's 54272 B
// double-buffer dropped occupancy to 2 blocks: the usable LDS ceiling is
// ~53 KB x 3, not 54.6 KB) + R16's two proven/structural wins:
//  * XCD-aware block swizzle (R16-proven: FETCH_SIZE 158 MB -> 29 MB; K/V
//    L2-resident per XCD, staging latency ~200 cyc instead of ~900).
//  * Pipelined P round trip WITHOUT a second buffer: order per chunk is
//    computeS(c+1) -> lgkmcnt(0) -> read aP(c) -> PV(c) -> write P(c+1).
//    The same-slot WAR (write P(c+1) over just-read P(c)) is safe: DS ops
//    execute in issue order within a wave, and the compiler preserves the
//    read->write program order through the may-alias Ps accesses.  The R5
//    fence (write->read RAW) remains, now hidden behind the S-MFMA cluster.
// Kept (HW-proven): S^T orientation, Ks[128][72] + bias-in-LDS broadcast
// k-step, Ps stride 36, Q fragments direct from global, short-live-range
// staging, s_setprio around MFMA clusters.
// ---------------------------------------------------------------------------
__global__ __launch_bounds__(256, 3) void attn_kernel(
    const ushort_ma* __restrict__ Qg,  // (64, 2304, 64), pre-scaled
    const ushort_ma* __restrict__ Kg,  // (64, 2304, 64)
    const ushort_ma* __restrict__ Vg,  // (64, 64, 2304)  (V^T)
    const float* __restrict__ lwp,     // locality_weight fp32 [8]
    unsigned short* __restrict__ Og)   // (8, 2304, 512): b, np, h*64+d
{
  __shared__ __align__(16) ushort_ma Ks[128][72];
  __shared__ __align__(16) ushort_ma Vs[64][136];
  __shared__ __align__(16) ushort_ma Ps[4][32][36];
  // total LDS = 18432 + 17408 + 9216 = 45056 B -> 3 blocks/CU

  // XCD-aware swizzle: 1152 blocks = 8 XCDs x 144; give each XCD 8 whole bh
  const int orig = blockIdx.x;
  const int v = (orig & 7) * 144 + (orig >> 3);
  const int bh = v / 18;
  const int q0 = (v - bh * 18) * 128;
  const int b = bh >> 3, h = bh & 7;
  const int t = threadIdx.x;
  const int lane = t & 63;
  const int w = t >> 6;
  const int lr = lane & 15, lq = lane >> 4;

  // Q fragments straight from global: rows are contiguous 128 B -> coalesced.
  const ushort_ma* Qw = Qg + ((size_t)bh * NTOK + q0 + (size_t)w * 32) * HD;
  bf16x8 aQ[2][2];
#pragma unroll
  for (int mi = 0; mi < 2; mi++)
#pragma unroll
    for (int ks = 0; ks < 2; ks++)
      aQ[mi][ks] = __builtin_bit_cast(
          bf16x8, *(const u32x4*)(Qw + (size_t)(mi * 16 + lr) * HD + ks * 32 + lq * 8));

  const float cb2 = -0.5f * LOG2E * lwp[h];  // bias_log2 = cb2 * dist2
  // Q-side bias extension fragment (n=lr; k slots on lq==0 only)
  bf16x8 aQb[2];
#pragma unroll
  for (int mi = 0; mi < 2; mi++) {
    const int qrow = q0 + w * 32 + mi * 16 + lr;
    const int yy = qrow / 48;
    const int xx = qrow - yy * 48;
    const float fy = (float)yy * (1.0f / 47.0f);
    const float fx = (float)xx * (1.0f / 47.0f);
    u32x4 vv = {0u, 0u, 0u, 0u};
    if (lq == 0) {
      vv[0] = (unsigned int)f2bf(fy) | ((unsigned int)f2bf(fx) << 16);
      vv[1] = (unsigned int)f2bf(fy * fy + fx * fx) | (0x3F80u << 16);
    }
    aQb[mi] = __builtin_bit_cast(bf16x8, vv);
  }

  // ones B-fragment for the l-MFMA
  const u32x4 onesU = {0x3F803F80u, 0x3F803F80u, 0x3F803F80u, 0x3F803F80u};
  const bf16x8 bOnes = __builtin_bit_cast(bf16x8, onesU);

  const f32x4 fz = {0.f, 0.f, 0.f, 0.f};
  f32x4 accO[2][4];
  f32x4 accL[2];
#pragma unroll
  for (int mi = 0; mi < 2; mi++) {
    accL[mi] = fz;
#pragma unroll
    for (int nd = 0; nd < 4; nd++) accO[mi][nd] = fz;
  }

  const ushort_ma* Kb = Kg + (size_t)bh * NTOK * HD;
  const ushort_ma* Vb = Vg + (size_t)bh * HD * NTOK;

  // S-MFMA for chunk cc (2 data k-steps + bias broadcast), into out[2][2]
  auto computeS = [&](int cc, f32x4 (&out)[2][2]) {
#pragma unroll
    for (int mi = 0; mi < 2; mi++) { out[mi][0] = fz; out[mi][1] = fz; }
    __builtin_amdgcn_s_setprio(1);
#pragma unroll
    for (int e2 = 0; e2 < 2; e2++) {
      const int ni = 2 * cc + e2;
#pragma unroll
      for (int ks = 0; ks < 2; ks++) {
        const bf16x8 bK = __builtin_bit_cast(
            bf16x8, *(const u32x4*)(&Ks[ni * 16 + lr][ks * 32 + lq * 8]));
#pragma unroll
        for (int mi = 0; mi < 2; mi++)
          out[mi][e2] = __builtin_amdgcn_mfma_f32_16x16x32_bf16(bK, aQ[mi][ks], out[mi][e2], 0, 0, 0);
      }
      // bias k-step: broadcast b128 (same addr across lq -> 2-way, free);
      // wrong-k lanes multiply aQb's zeros.
      const bf16x8 bKb = __builtin_bit_cast(
          bf16x8, *(const u32x4*)(&Ks[ni * 16 + lr][64]));
#pragma unroll
      for (int mi = 0; mi < 2; mi++)
        out[mi][e2] = __builtin_amdgcn_mfma_f32_16x16x32_bf16(bKb, aQb[mi], out[mi][e2], 0, 0, 0);
    }
    __builtin_amdgcn_s_setprio(0);
  };

  // exp2 + pack + ds_write_b64 into Ps
  auto packP = [&](f32x4 (&sin)[2][2]) {
#pragma unroll
    for (int mi = 0; mi < 2; mi++)
#pragma unroll
      for (int e2 = 0; e2 < 2; e2++) {
        unsigned int pb[4];
#pragma unroll
        for (int r = 0; r < 4; r++) {
          const float p = __builtin_amdgcn_exp2f(sin[mi][e2][r]);
          pb[r] = (__builtin_bit_cast(unsigned int, p) >> 16) & 0xFFFFu;
        }
        u32x2 pk;
        pk[0] = pb[0] | (pb[1] << 16);
        pk[1] = pb[2] | (pb[3] << 16);
        *(u32x2*)(&Ps[w][mi * 16 + lr][e2 * 16 + lq * 4]) = pk;
      }
  };

  for (int kt = 0; kt < 18; kt++) {
    const int kv0 = kt * 128;
    __syncthreads();  // WAR: previous tile's readers done
    {
      u32x4 kc[4], vc[4];
#pragma unroll
      for (int it = 0; it < 4; it++) {
        const int q = t + it * 256;
        kc[it] = *(const u32x4*)(Kb + (size_t)(kv0 + (q >> 3)) * HD + (q & 7) * 8);
        vc[it] = *(const u32x4*)(Vb + (size_t)(q >> 4) * NTOK + kv0 + (q & 15) * 8);
      }
#pragma unroll
      for (int it = 0; it < 4; it++) {
        const int q = t + it * 256;
        *(u32x4*)(&Ks[q >> 3][(q & 7) * 8]) = kc[it];
        *(u32x4*)(&Vs[q >> 4][(q & 15) * 8]) = vc[it];
      }
    }
    // K-side bias extension for this tile's 128 kv rows (cols 64..71),
    // computed ONCE per tile by 128 threads
    if (t < 128) {
      const int kv = kv0 + t;
      const int yy = kv / 48;
      const int xx = kv - yy * 48;
      const float fy = (float)yy * (1.0f / 47.0f);
      const float fx = (float)xx * (1.0f / 47.0f);
      u32x4 bv;
      bv[0] = (unsigned int)f2bf(-2.0f * cb2 * fy) |
              ((unsigned int)f2bf(-2.0f * cb2 * fx) << 16);
      bv[1] = (unsigned int)f2bf(cb2) |
              ((unsigned int)f2bf(cb2 * (fy * fy + fx * fx)) << 16);
      bv[2] = 0u;
      bv[3] = 0u;
      *(u32x4*)(&Ks[t][64]) = bv;
    }
    __syncthreads();  // tile ready

    // pipelined chunk loop: the P write->read fence hides behind the next
    // chunk's S-MFMA cluster; single Ps buffer (in-wave DS ordering makes
    // the read->write WAR safe)
    f32x4 s2[2][2];
    computeS(0, s2);
    packP(s2);
#pragma unroll
    for (int c = 0; c < 4; c++) {
      if (c < 3) computeS(c + 1, s2);
      // HW completion fence: P(c) writes (issued before the S-MFMA cluster
      // above) are drained here
      __asm__ volatile("s_waitcnt lgkmcnt(0)" ::: "memory");
      bf16x8 aP[2];
#pragma unroll
      for (int mi = 0; mi < 2; mi++)
        aP[mi] = __builtin_bit_cast(
            bf16x8, *(const u32x4*)(&Ps[w][mi * 16 + lr][lq * 8]));
      __builtin_amdgcn_s_setprio(1);
#pragma unroll
      for (int nd = 0; nd < 4; nd++) {
        const bf16x8 bV = __builtin_bit_cast(
            bf16x8, *(const u32x4*)(&Vs[nd * 16 + lr][c * 32 + lq * 8]));
#pragma unroll
        for (int mi = 0; mi < 2; mi++)
          accO[mi][nd] = __builtin_amdgcn_mfma_f32_16x16x32_bf16(aP[mi], bV, accO[mi][nd], 0, 0, 0);
      }
      // l += P x ones (exact same aP operand -> perfect num/denom consistency)
#pragma unroll
      for (int mi = 0; mi < 2; mi++)
        accL[mi] = __builtin_amdgcn_mfma_f32_16x16x32_bf16(aP[mi], bOnes, accL[mi], 0, 0, 0);
      __builtin_amdgcn_s_setprio(0);
      if (c < 3) packP(s2);  // write P(c+1) after aP(c) reads (in-order DS)
    }
  }

  // normalize and store: accL C-layout row matches accO row exactly
#pragma unroll
  for (int mi = 0; mi < 2; mi++) {
    f32x4 inv;
#pragma unroll
    for (int r = 0; r < 4; r++) inv[r] = 1.0f / accL[mi][r];
#pragma unroll
    for (int nd = 0; nd < 4; nd++)
#pragma unroll
      for (int r = 0; r < 4; r++) {
        const int np = q0 + w * 32 + mi * 16 + lq * 4 + r;
        Og[((size_t)(b * NTOK + np)) * CDIM + h * HD + nd * 16 + lr] =
            f2bf(accO[mi][nd][r] * inv[r]);
      }
  }
}

extern "C" void kernel_launch(void* const* d_in, const int* in_sizes, int n_in,
                              void* d_out, int out_size, void* d_ws, size_t ws_size,
                              hipStream_t stream) {
  const float* x      = (const float*)d_in[0];
  const float* qkv_w  = (const float*)d_in[1];
  const float* proj_w = (const float*)d_in[2];
  const float* proj_b = (const float*)d_in[3];
  const float* temp   = (const float*)d_in[4];
  const float* lw     = (const float*)d_in[5];

  ushort_ma* base = (ushort_ma*)d_ws;
  ushort_ma* XB  = base + OFF_XO;   // x bf16; overlaid by O after gemm1
  ushort_ma* WQB = base + OFF_WQ;
  ushort_ma* WPB = base + OFF_WP;
  ushort_ma* Q   = base + OFF_Q;
  ushort_ma* Kt  = base + OFF_K;
  ushort_ma* Vt  = base + OFF_V;
  ushort_ma* O   = XB;              // overlay: XB dead after gemm1

  convert3<<<1024, 256, 0, stream>>>(x, qkv_w, proj_w, base);
  gemm_bt<0><<<dim3(MROWS / 128, 1536 / 128), 256, 0, stream>>>(
      XB, WQB, temp, (unsigned short*)Q, (unsigned short*)Kt, (unsigned short*)Vt);
  attn_kernel<<<dim3((NTOK / 128) * BATCH * NH), 256, 0, stream>>>(
      Q, Kt, Vt, lw, (unsigned short*)O);
  gemm_bt<1><<<dim3(MROWS / 128, CDIM / 128), 256, 0, stream>>>(
      O, WPB, proj_b, (unsigned short*)d_out, nullptr, nullptr);
}

// Round 11
// 275.538 us; speedup vs baseline: 1.0911x; 1.0674x over previous
//
#include <hip/hip_runtime.h>

typedef unsigned int   uint_ma   __attribute__((may_alias));
typedef unsigned short ushort_ma __attribute__((may_alias));
typedef float          float_ma  __attribute__((may_alias));
typedef __bf16 bf16x8 __attribute__((ext_vector_type(8)));
typedef float f32x4 __attribute__((ext_vector_type(4)));
typedef uint_ma u32x4 __attribute__((ext_vector_type(4)));
typedef uint_ma u32x2 __attribute__((ext_vector_type(2)));
typedef ushort_ma u16x4 __attribute__((ext_vector_type(4)));

#define BATCH 8
#define NTOK 2304
#define CDIM 512
#define NH 8
#define HD 64
#define MROWS (BATCH * NTOK)  // 18432
#define LOG2E 1.44269504088896f

// ---- workspace layout (bf16 element offsets) ------------------------------
constexpr size_t N_X  = (size_t)BATCH * NTOK * CDIM;  // 9,437,184
constexpr size_t N_WQ = (size_t)3 * CDIM * CDIM;      //   786,432
constexpr size_t N_WP = (size_t)CDIM * CDIM;          //   262,144
constexpr size_t OFF_XO = 0;              // X for gemm1; O overlay after
constexpr size_t OFF_WQ = OFF_XO + N_X;
constexpr size_t OFF_WP = OFF_WQ + N_WQ;
constexpr size_t OFF_Q  = OFF_WP + N_WP;
constexpr size_t OFF_K  = OFF_Q + N_X;
constexpr size_t OFF_V  = OFF_K + N_X;   // V tiled: (bh, 18, 64, 128) — same size
constexpr size_t CV8 = (N_X + N_WQ + N_WP) / 8;  // 1,310,720

__device__ __forceinline__ float bf2f(unsigned short h) {
  unsigned int u = ((unsigned int)h) << 16;
  return __builtin_bit_cast(float, u);
}
__device__ __forceinline__ unsigned short f2bf(float f) {
  unsigned int u = __builtin_bit_cast(unsigned int, f);
  u += 0x7fffu + ((u >> 16) & 1u);  // RNE
  return (unsigned short)(u >> 16);
}

// async global -> LDS, 16B per lane (dest = wave-uniform base + lane*16;
// global source address is PER-LANE -> pre-swizzled source enables swizzled
// LDS layouts with a linear dest, the m173/m201 pattern)
__device__ __forceinline__ void gload16(const void* g, void* l) {
  __builtin_amdgcn_global_load_lds(
      (const __attribute__((address_space(1))) void*)g,
      (__attribute__((address_space(3))) void*)l, 16, 0, 0);
}

// ---------------------------------------------------------------------------
// Convert x, qkv_w, proj_w (fp32) -> bf16 in ws.
// ---------------------------------------------------------------------------
__global__ __launch_bounds__(256) void convert3(
    const float* __restrict__ s0, const float* __restrict__ s1,
    const float* __restrict__ s2, ushort_ma* __restrict__ base) {
  const size_t gid = (size_t)blockIdx.x * blockDim.x + threadIdx.x;
  const size_t stride = (size_t)gridDim.x * blockDim.x;
  for (size_t i = gid; i < CV8; i += stride) {
    size_t r = i;
    const float* src;
    size_t doff;
    if (r < N_X / 8) { src = s0; doff = OFF_XO; }
    else if ((r -= N_X / 8) < N_WQ / 8) { src = s1; doff = OFF_WQ; }
    else { r -= N_WQ / 8; src = s2; doff = OFF_WP; }
    const f32x4* fw = (const f32x4*)(src + r * 8);
    const f32x4 a = fw[0], b = fw[1];
    u16x4 lo, hi;
#pragma unroll
    for (int j = 0; j < 4; j++) { lo[j] = f2bf(a[j]); hi[j] = f2bf(b[j]); }
    ushort_ma* dst = base + doff + r * 8;
    *(u16x4*)dst = lo;
    *(u16x4*)(dst + 4) = hi;
  }
}

// ---------------------------------------------------------------------------
// C = A (M x 512) * W^T (contraction K=512), m97-style staging:
// global_load_lds width=16, double-buffered LDS, 1 barrier/iter.
// Transposed-C MFMA (R9-proven).  R18 change: V^T written PRE-TILED as
// (bh, kt=np>>7, d, kv_in_tile=np&127) so each (bh,kt) V-tile is a
// contiguous 16384 B block (gload16-able in attn).  Same total size.
// ---------------------------------------------------------------------------
template <int MODE>
__global__ __launch_bounds__(256, 3) void gemm_bt(
    const ushort_ma* __restrict__ A, const ushort_ma* __restrict__ W,
    const float* __restrict__ aux,   // MODE0: temperature[8]; MODE1: proj_b[512]
    unsigned short* __restrict__ o0, // MODE0: Q (64,2304,64); MODE1: fp32 out
    unsigned short* __restrict__ o1, // MODE0: K (64,2304,64)
    unsigned short* __restrict__ o2) // MODE0: V tiled (64,18,64,128)
{
  __shared__ __align__(16) ushort_ma As[2][128][32];
  __shared__ __align__(16) ushort_ma Bs[2][128][32];
  const int K = CDIM;
  const int m0 = blockIdx.x * 128;
  const int n0 = blockIdx.y * 128;
  const int t = threadIdx.x;
  const int lane = t & 63;
  const int w = t >> 6;
  const int wm = (w >> 1) * 64, wn = (w & 1) * 64;
  const int lr = lane & 15, lq = lane >> 4;

  const int srow = w * 16 + (lane >> 2);
  const int scg = (lane & 3) ^ ((srow >> 1) & 3);
  const ushort_ma* Ag0 = A + (size_t)(m0 + srow) * K + scg * 8;
  const ushort_ma* Ag1 = Ag0 + (size_t)64 * K;
  const ushort_ma* Bg0 = W + (size_t)(n0 + srow) * K + scg * 8;
  const ushort_ma* Bg1 = Bg0 + (size_t)64 * K;

  const f32x4 fz = {0.f, 0.f, 0.f, 0.f};
  f32x4 acc[4][4];
#pragma unroll
  for (int i = 0; i < 4; i++)
#pragma unroll
    for (int j = 0; j < 4; j++) acc[i][j] = fz;

  auto issue = [&](int kt, int buf) {
    const int k0 = kt * 32;
    gload16(Ag0 + k0, (void*)&As[buf][w * 16][0]);
    gload16(Ag1 + k0, (void*)&As[buf][64 + w * 16][0]);
    gload16(Bg0 + k0, (void*)&Bs[buf][w * 16][0]);
    gload16(Bg1 + k0, (void*)&Bs[buf][64 + w * 16][0]);
  };

  issue(0, 0);
  const int colf = 8 * (lq ^ ((lr >> 1) & 3));

  for (int kt = 0; kt < 16; kt++) {
    const int buf = kt & 1;
    __syncthreads();  // drains vmcnt(0): tile kt landed; prev readers done
    if (kt < 15) issue(kt + 1, buf ^ 1);
    bf16x8 af[4], bfr[4];
#pragma unroll
    for (int i = 0; i < 4; i++)
      af[i] = __builtin_bit_cast(bf16x8, *(const u32x4*)(&As[buf][wm + i * 16 + lr][colf]));
#pragma unroll
    for (int j = 0; j < 4; j++)
      bfr[j] = __builtin_bit_cast(bf16x8, *(const u32x4*)(&Bs[buf][wn + j * 16 + lr][colf]));
#pragma unroll
    for (int i = 0; i < 4; i++)
#pragma unroll
      for (int j = 0; j < 4; j++)
        acc[i][j] = __builtin_amdgcn_mfma_f32_16x16x32_bf16(bfr[j], af[i], acc[i][j], 0, 0, 0);
  }

  // Epilogue, transposed-C layout: acc[i][j][r] = C[gm][gc] with
  //   gm = m0 + wm + i*16 + lr
  //   gc = n0 + wn + j*16 + lq*4 + r
  if (MODE == 0) {
#pragma unroll
    for (int j = 0; j < 4; j++) {
      const int gcb = n0 + wn + j * 16 + lq * 4;  // 4-aligned, no 64/512 straddle
      const int which = gcb >> 9;  // 0=q,1=k,2=v (uniform over r)
      const int h = (gcb >> 6) & 7;
      const int db = gcb & 63;
      // Q carries exp(temperature)*log2e so attention works in log2 domain
      const float sc = (which == 0) ? __expf(aux[h]) * LOG2E : 1.0f;
      unsigned short* dst = (which == 0) ? o0 : o1;
#pragma unroll
      for (int i = 0; i < 4; i++) {
        const int gm = m0 + wm + i * 16 + lr;
        const int b = gm / NTOK;
        const int np = gm - b * NTOK;
        if (which == 2) {
          // V tiled: (bh, np>>7, d, np&127)
          const size_t tb = (((size_t)(b * NH + h) * 18 + (np >> 7)) * HD) * 128 + (np & 127);
#pragma unroll
          for (int r = 0; r < 4; r++)
            o2[tb + (size_t)(db + r) * 128] = f2bf(acc[i][j][r]);
        } else {
          u16x4 pk;
#pragma unroll
          for (int r = 0; r < 4; r++) pk[r] = f2bf(acc[i][j][r] * sc);
          *(u16x4*)(dst + ((size_t)((b * NH + h) * NTOK + np)) * HD + db) = pk;
        }
      }
    }
  } else {
    float_ma* outf = (float_ma*)o0;
#pragma unroll
    for (int j = 0; j < 4; j++) {
      const int gcb = n0 + wn + j * 16 + lq * 4;
      const f32x4 bv4 = *(const f32x4*)(aux + gcb);
#pragma unroll
      for (int i = 0; i < 4; i++) {
        const int gm = m0 + wm + i * 16 + lr;
        f32x4 ov;
#pragma unroll
        for (int r = 0; r < 4; r++) ov[r] = acc[i][j][r] + bv4[r];
        *(f32x4*)(outf + (size_t)gm * CDIM + gcb) = ov;
      }
    }
  }
}

// ---------------------------------------------------------------------------
// Flash attention, log2-domain (R6 bias fold, R9 S^T, R15 Ps36, R16 XCD
// swizzle, R17 single-buffer pipeline — all HW-proven).
// R18: K/V staging via global_load_lds (async, zero registers, zero
// ds_writes) with the both-sides XOR swizzle:
//  * Ks flat [128][64] (rows 128 B = 8 col16-groups), Vs flat [64][128]
//    (rows 256 B = 16 col16-groups).  Logical (row, C) stored at physical
//    C ^ (row&7) -> read banks uniform (8 dw/bank floor, verified).
//  * gload16 writes LDS linearly; the per-lane GLOBAL source address is
//    pre-swizzled so data lands at its swizzled slot.  For Ks, row&7 ==
//    lane>>3 (j-invariant); for Vs row&7 = 4*(j&1) + lane>>4 (two patterns).
//  * V read from the gemm0-pre-tiled (bh,kt,64,128) contiguous blocks.
//  * Bias now in a separate Bs[128][8] (2 KB) -> no ordering hazard with
//    the async loads; broadcast b128 reads unchanged in cost.
// LDS = 16384 + 16384 + 2048 + 9216 = 44032 B -> 3 blocks/CU.
// ---------------------------------------------------------------------------
__global__ __launch_bounds__(256, 3) void attn_kernel(
    const ushort_ma* __restrict__ Qg,  // (64, 2304, 64), pre-scaled
    const ushort_ma* __restrict__ Kg,  // (64, 2304, 64)
    const ushort_ma* __restrict__ Vg,  // (64, 18, 64, 128) pre-tiled V^T
    const float* __restrict__ lwp,     // locality_weight fp32 [8]
    unsigned short* __restrict__ Og)   // (8, 2304, 512): b, np, h*64+d
{
  __shared__ __align__(16) ushort_ma Ks[128 * 64];  // flat, col^row&7 swizzled
  __shared__ __align__(16) ushort_ma Vs[64 * 128];  // flat, col^row&7 swizzled
  __shared__ __align__(16) ushort_ma Bsb[128][8];   // bias ext (16 B rows)
  __shared__ __align__(16) ushort_ma Ps[4][32][36];
  // total LDS = 16384 + 16384 + 2048 + 9216 = 44032 B -> 3 blocks/CU

  // XCD-aware swizzle: 1152 blocks = 8 XCDs x 144; give each XCD 8 whole bh
  const int orig = blockIdx.x;
  const int v = (orig & 7) * 144 + (orig >> 3);
  const int bh = v / 18;
  const int q0 = (v - bh * 18) * 128;
  const int b = bh >> 3, h = bh & 7;
  const int t = threadIdx.x;
  const int lane = t & 63;
  const int w = t >> 6;
  const int lr = lane & 15, lq = lane >> 4;
  const int lr7 = lr & 7;

  // Q fragments straight from global: rows are contiguous 128 B -> coalesced.
  const ushort_ma* Qw = Qg + ((size_t)bh * NTOK + q0 + (size_t)w * 32) * HD;
  bf16x8 aQ[2][2];
#pragma unroll
  for (int mi = 0; mi < 2; mi++)
#pragma unroll
    for (int ks = 0; ks < 2; ks++)
      aQ[mi][ks] = __builtin_bit_cast(
          bf16x8, *(const u32x4*)(Qw + (size_t)(mi * 16 + lr) * HD + ks * 32 + lq * 8));

  const float cb2 = -0.5f * LOG2E * lwp[h];  // bias_log2 = cb2 * dist2
  // Q-side bias extension fragment (n=lr; k slots on lq==0 only)
  bf16x8 aQb[2];
#pragma unroll
  for (int mi = 0; mi < 2; mi++) {
    const int qrow = q0 + w * 32 + mi * 16 + lr;
    const int yy = qrow / 48;
    const int xx = qrow - yy * 48;
    const float fy = (float)yy * (1.0f / 47.0f);
    const float fx = (float)xx * (1.0f / 47.0f);
    u32x4 vv = {0u, 0u, 0u, 0u};
    if (lq == 0) {
      vv[0] = (unsigned int)f2bf(fy) | ((unsigned int)f2bf(fx) << 16);
      vv[1] = (unsigned int)f2bf(fy * fy + fx * fx) | (0x3F80u << 16);
    }
    aQb[mi] = __builtin_bit_cast(bf16x8, vv);
  }

  // ones B-fragment for the l-MFMA
  const u32x4 onesU = {0x3F803F80u, 0x3F803F80u, 0x3F803F80u, 0x3F803F80u};
  const bf16x8 bOnes = __builtin_bit_cast(bf16x8, onesU);

  const f32x4 fz = {0.f, 0.f, 0.f, 0.f};
  f32x4 accO[2][4];
  f32x4 accL[2];
#pragma unroll
  for (int mi = 0; mi < 2; mi++) {
    accL[mi] = fz;
#pragma unroll
    for (int nd = 0; nd < 4; nd++) accO[mi][nd] = fz;
  }

  // --- staging source addresses (pre-swizzled per lane) ---
  // Ks: instr j covers rows j*8 + (lane>>3), col16 = lane&7; row&7 == lane>>3
  const int kl8 = lane >> 3;             // 0..7
  const ushort_ma* Kb = Kg + (size_t)bh * NTOK * HD;
  const ushort_ma* Ksrc = Kb + (size_t)kl8 * 64 + (size_t)((lane & 7) ^ kl8) * 8;
  // Vs: instr j covers rows j*4 + (lane>>4), col16 = lane&15;
  // row&7 = 4*(j&1) + (lane>>4) -> two per-lane source patterns
  const int vr4 = lane >> 4;             // 0..3
  const int v16 = lane & 15;
  const ushort_ma* Vtile0 = Vg + (size_t)bh * 18 * (HD * 128);
  const size_t vlaneE = (size_t)vr4 * 128 + (size_t)(v16 ^ vr4) * 8;
  const size_t vlaneO = (size_t)vr4 * 128 + (size_t)(v16 ^ (4 + vr4)) * 8;

  // --- per-lane LDS read offsets (bytes) for the swizzled layouts ---
  const int kb_lane = lr * 128;              // Ks row base
  const int colK0 = ((0 * 4 + lq) ^ lr7) << 4;
  const int colK1 = ((1 * 4 + lq) ^ lr7) << 4;
  const int vb_lane = lr * 256;              // Vs row base
  int colV[4];
#pragma unroll
  for (int c = 0; c < 4; c++) colV[c] = ((c * 4 + lq) ^ lr7) << 4;

  // S-MFMA for chunk cc (2 data k-steps + bias broadcast), into out[2][2]
  auto computeS = [&](int cc, f32x4 (&out)[2][2]) {
#pragma unroll
    for (int mi = 0; mi < 2; mi++) { out[mi][0] = fz; out[mi][1] = fz; }
    __builtin_amdgcn_s_setprio(1);
#pragma unroll
    for (int e2 = 0; e2 < 2; e2++) {
      const int ni = 2 * cc + e2;
      const bf16x8 bK0 = __builtin_bit_cast(
          bf16x8, *(const u32x4*)((const char*)Ks + ni * 2048 + kb_lane + colK0));
      const bf16x8 bK1 = __builtin_bit_cast(
          bf16x8, *(const u32x4*)((const char*)Ks + ni * 2048 + kb_lane + colK1));
#pragma unroll
      for (int mi = 0; mi < 2; mi++) {
        out[mi][e2] = __builtin_amdgcn_mfma_f32_16x16x32_bf16(bK0, aQ[mi][0], out[mi][e2], 0, 0, 0);
        out[mi][e2] = __builtin_amdgcn_mfma_f32_16x16x32_bf16(bK1, aQ[mi][1], out[mi][e2], 0, 0, 0);
      }
      // bias k-step: broadcast b128 from Bsb (2-way banks, wrong-k lanes
      // multiply aQb's zeros)
      const bf16x8 bKb = __builtin_bit_cast(
          bf16x8, *(const u32x4*)(&Bsb[ni * 16 + lr][0]));
#pragma unroll
      for (int mi = 0; mi < 2; mi++)
        out[mi][e2] = __builtin_amdgcn_mfma_f32_16x16x32_bf16(bKb, aQb[mi], out[mi][e2], 0, 0, 0);
    }
    __builtin_amdgcn_s_setprio(0);
  };

  // exp2 + pack + ds_write_b64 into Ps
  auto packP = [&](f32x4 (&sin)[2][2]) {
#pragma unroll
    for (int mi = 0; mi < 2; mi++)
#pragma unroll
      for (int e2 = 0; e2 < 2; e2++) {
        unsigned int pb[4];
#pragma unroll
        for (int r = 0; r < 4; r++) {
          const float p = __builtin_amdgcn_exp2f(sin[mi][e2][r]);
          pb[r] = (__builtin_bit_cast(unsigned int, p) >> 16) & 0xFFFFu;
        }
        u32x2 pk;
        pk[0] = pb[0] | (pb[1] << 16);
        pk[1] = pb[2] | (pb[3] << 16);
        *(u32x2*)(&Ps[w][mi * 16 + lr][e2 * 16 + lq * 4]) = pk;
      }
  };

  for (int kt = 0; kt < 18; kt++) {
    const int kv0 = kt * 128;
    __syncthreads();  // WAR: previous tile's readers done
    // async staging: 16 K-instrs + 16 V-instrs, 4+4 per wave, zero registers
    {
      const ushort_ma* KsT = Ksrc + (size_t)kv0 * 64;
      const ushort_ma* VtE = Vtile0 + (size_t)kt * (HD * 128) + vlaneE;
      const ushort_ma* VtO = Vtile0 + (size_t)kt * (HD * 128) + vlaneO;
#pragma unroll
      for (int jj = 0; jj < 4; jj++) {
        const int j = w + jj * 4;
        gload16(KsT + (size_t)j * 512, (void*)((char*)Ks + j * 1024));
        const ushort_ma* vs = (j & 1) ? (VtO + (size_t)j * 512) : (VtE + (size_t)j * 512);
        gload16(vs, (void*)((char*)Vs + j * 1024));
      }
    }
    // K-side bias extension for this tile's 128 kv rows -> Bsb
    if (t < 128) {
      const int kv = kv0 + t;
      const int yy = kv / 48;
      const int xx = kv - yy * 48;
      const float fy = (float)yy * (1.0f / 47.0f);
      const float fx = (float)xx * (1.0f / 47.0f);
      u32x4 bv;
      bv[0] = (unsigned int)f2bf(-2.0f * cb2 * fy) |
              ((unsigned int)f2bf(-2.0f * cb2 * fx) << 16);
      bv[1] = (unsigned int)f2bf(cb2) |
              ((unsigned int)f2bf(cb2 * (fy * fy + fx * fx)) << 16);
      bv[2] = 0u;
      bv[3] = 0u;
      *(u32x4*)(&Bsb[t][0]) = bv;
    }
    __syncthreads();  // drains vmcnt (gload16) + lgkm (bias write): tile ready

    // pipelined chunk loop (R17-proven): fence hides behind next chunk's
    // S-MFMAs; single Ps buffer (in-wave DS ordering makes the WAR safe)
    f32x4 s2[2][2];
    computeS(0, s2);
    packP(s2);
#pragma unroll
    for (int c = 0; c < 4; c++) {
      if (c < 3) computeS(c + 1, s2);
      __asm__ volatile("s_waitcnt lgkmcnt(0)" ::: "memory");
      bf16x8 aP[2];
#pragma unroll
      for (int mi = 0; mi < 2; mi++)
        aP[mi] = __builtin_bit_cast(
            bf16x8, *(const u32x4*)(&Ps[w][mi * 16 + lr][lq * 8]));
      __builtin_amdgcn_s_setprio(1);
#pragma unroll
      for (int nd = 0; nd < 4; nd++) {
        const bf16x8 bV = __builtin_bit_cast(
            bf16x8, *(const u32x4*)((const char*)Vs + nd * 4096 + vb_lane + colV[c]));
#pragma unroll
        for (int mi = 0; mi < 2; mi++)
          accO[mi][nd] = __builtin_amdgcn_mfma_f32_16x16x32_bf16(aP[mi], bV, accO[mi][nd], 0, 0, 0);
      }
      // l += P x ones (exact same aP operand -> perfect num/denom consistency)
#pragma unroll
      for (int mi = 0; mi < 2; mi++)
        accL[mi] = __builtin_amdgcn_mfma_f32_16x16x32_bf16(aP[mi], bOnes, accL[mi], 0, 0, 0);
      __builtin_amdgcn_s_setprio(0);
      if (c < 3) packP(s2);  // write P(c+1) after aP(c) reads (in-order DS)
    }
  }

  // normalize and store: accL C-layout row matches accO row exactly
#pragma unroll
  for (int mi = 0; mi < 2; mi++) {
    f32x4 inv;
#pragma unroll
    for (int r = 0; r < 4; r++) inv[r] = 1.0f / accL[mi][r];
#pragma unroll
    for (int nd = 0; nd < 4; nd++)
#pragma unroll
      for (int r = 0; r < 4; r++) {
        const int np = q0 + w * 32 + mi * 16 + lq * 4 + r;
        Og[((size_t)(b * NTOK + np)) * CDIM + h * HD + nd * 16 + lr] =
            f2bf(accO[mi][nd][r] * inv[r]);
      }
  }
}

extern "C" void kernel_launch(void* const* d_in, const int* in_sizes, int n_in,
                              void* d_out, int out_size, void* d_ws, size_t ws_size,
                              hipStream_t stream) {
  const float* x      = (const float*)d_in[0];
  const float* qkv_w  = (const float*)d_in[1];
  const float* proj_w = (const float*)d_in[2];
  const float* proj_b = (const float*)d_in[3];
  const float* temp   = (const float*)d_in[4];
  const float* lw     = (const float*)d_in[5];

  ushort_ma* base = (ushort_ma*)d_ws;
  ushort_ma* XB  = base + OFF_XO;   // x bf16; overlaid by O after gemm1
  ushort_ma* WQB = base + OFF_WQ;
  ushort_ma* WPB = base + OFF_WP;
  ushort_ma* Q   = base + OFF_Q;
  ushort_ma* Kt  = base + OFF_K;
  ushort_ma* Vt  = base + OFF_V;
  ushort_ma* O   = XB;              // overlay: XB dead after gemm1

  convert3<<<1024, 256, 0, stream>>>(x, qkv_w, proj_w, base);
  gemm_bt<0><<<dim3(MROWS / 128, 1536 / 128), 256, 0, stream>>>(
      XB, WQB, temp, (unsigned short*)Q, (unsigned short*)Kt, (unsigned short*)Vt);
  attn_kernel<<<dim3((NTOK / 128) * BATCH * NH), 256, 0, stream>>>(
      Q, Kt, Vt, lw, (unsigned short*)O);
  gemm_bt<1><<<dim3(MROWS / 128, CDIM / 128), 256, 0, stream>>>(
      O, WPB, proj_b, (unsigned short*)d_out, nullptr, nullptr);
}